// Round 1
// baseline (358.553 us; speedup 1.0000x reference)
//
#include <hip/hip_runtime.h>
#include <hip/hip_bf16.h>

// Problem constants
#define TT   512
#define DD   64
#define NWK  4
#define STP  16
#define NPJ  15          // others per w
#define NBLK 60          // NWK * NPJ
#define CMAT (TT * TT)   // floats per cost matrix
// u-domain scale: u = R / (gamma * ln2), gamma = 5
#define CSCALE 0.2885390081777927f
#define USCALE 3.4657359027997265f   // gamma * ln2
#define BIGC   2.885390081777927e8f  // 1e9 * CSCALE

// ---------------------------------------------------------------------------
// Kernel 1: cost matrices, scaled by CSCALE, clipped to la x lb (rounded to 32)
// grid (16, 16, nchunk); block 256
// ---------------------------------------------------------------------------
__global__ __launch_bounds__(256) void cost_kernel(const float* __restrict__ data,
                                                   const int* __restrict__ lens,
                                                   float* __restrict__ cost, int base) {
  int blk = base + blockIdx.z;
  int w = blk / NPJ, j = blk - w * NPJ;
  int la = lens[w * STP];
  int lb = lens[w * STP + 1 + j];
  int ti = blockIdx.y, tj = blockIdx.x;
  if (ti * 32 >= la || tj * 32 >= lb) return;

  __shared__ float As[32][65], Bs[32][65];
  __shared__ float a2s[32], b2s[32];

  const float* A = data + ((size_t)(w * STP) * TT + (size_t)ti * 32) * DD;
  const float* B = data + ((size_t)(w * STP + 1 + j) * TT + (size_t)tj * 32) * DD;

  int t = threadIdx.x;
  for (int v = 0; v < 2; ++v) {
    int idx = t + v * 256;          // float4 slot 0..511
    int r  = idx >> 4;              // row 0..31 (16 float4 per row)
    int c4 = (idx & 15) << 2;       // col 0,4,...,60
    float4 av = *(const float4*)(A + r * DD + c4);
    As[r][c4] = av.x; As[r][c4 + 1] = av.y; As[r][c4 + 2] = av.z; As[r][c4 + 3] = av.w;
    float4 bv = *(const float4*)(B + r * DD + c4);
    Bs[r][c4] = bv.x; Bs[r][c4 + 1] = bv.y; Bs[r][c4 + 2] = bv.z; Bs[r][c4 + 3] = bv.w;
  }
  __syncthreads();
  if (t < 64) {
    int r = t & 31;
    float s = 0.f;
    if (t < 32) { for (int k = 0; k < DD; ++k) s += As[r][k] * As[r][k]; a2s[r] = s; }
    else        { for (int k = 0; k < DD; ++k) s += Bs[r][k] * Bs[r][k]; b2s[r] = s; }
  }
  __syncthreads();

  int r = t >> 3, c0 = (t & 7) << 2;   // 4 cells per thread: (r, c0..c0+3)
  float acc0 = 0.f, acc1 = 0.f, acc2 = 0.f, acc3 = 0.f;
  for (int k = 0; k < DD; ++k) {
    float a = As[r][k];
    acc0 += a * Bs[c0][k];
    acc1 += a * Bs[c0 + 1][k];
    acc2 += a * Bs[c0 + 2][k];
    acc3 += a * Bs[c0 + 3][k];
  }
  float4 o;
  o.x = (a2s[r] + b2s[c0]     - 2.f * acc0) * CSCALE;
  o.y = (a2s[r] + b2s[c0 + 1] - 2.f * acc1) * CSCALE;
  o.z = (a2s[r] + b2s[c0 + 2] - 2.f * acc2) * CSCALE;
  o.w = (a2s[r] + b2s[c0 + 3] - 2.f * acc3) * CSCALE;
  float* Cp = cost + (size_t)blockIdx.z * CMAT + (size_t)(ti * 32 + r) * TT + tj * 32 + c0;
  *(float4*)Cp = o;
}

// ---------------------------------------------------------------------------
// Soft-DTW DP cell in u-units: u = dc + min - log2(1 + 2^(min-med) + 2^(min-max))
// ---------------------------------------------------------------------------
__device__ __forceinline__ float dpcell(float dc, float a, float b, float c) {
  float mn = fminf(fminf(a, b), c);
  float mx = fmaxf(fmaxf(a, b), c);
  float md = __builtin_amdgcn_fmed3f(a, b, c);
  float e = 1.0f + __builtin_amdgcn_exp2f(mn - md) + __builtin_amdgcn_exp2f(mn - mx);
  return dc + mn - __builtin_amdgcn_logf(e);
}

// ---------------------------------------------------------------------------
// Kernel 2: wavefront DP, one block per (w,j); 2x2 tile per thread, 256 threads
// ---------------------------------------------------------------------------
__global__ __launch_bounds__(256) void dp_kernel(const float* __restrict__ cost,
                                                 const int* __restrict__ lens,
                                                 float* __restrict__ sdt, int base) {
  int blk = base + blockIdx.x;
  int w = blk / NPJ, j = blk - w * NPJ;
  int la = lens[w * STP];
  int lb = lens[w * STP + 1 + j];
  const float* C = cost + (size_t)blockIdx.x * CMAT;
  int nI = (la + 1) >> 1, nJ = (lb + 1) >> 1;
  int I = threadIdx.x;
  int steps = nI + nJ - 1;

  __shared__ float bot[2][256][2];

  bool act = (I < nI);
  bool row1ok = (2 * I + 1) < la;
  int Itar = (la - 1) >> 1, Jtar = (lb - 1) >> 1;

  float L0 = BIGC, L1 = BIGC, D0 = (I == 0) ? 0.0f : BIGC;
  float d00 = 0.f, d01 = 0.f, d10 = 0.f, d11 = 0.f;
  if (I == 0) { d00 = C[0]; d01 = C[1]; d10 = C[TT]; d11 = C[TT + 1]; }

  for (int s = 0; s < steps; ++s) {
    int J = s - I;
    bool live = act && (J >= 0) && (J < nJ);
    // issue prefetch for next tile (I, J+1)
    int Jn = J + 1;
    bool pf = act && (Jn >= 0) && (Jn < nJ);
    float q00 = 0.f, q01 = 0.f, q10 = 0.f, q11 = 0.f;
    if (pf) {
      const float* cp = C + (size_t)(2 * I) * TT + 2 * Jn;
      q00 = cp[0]; q01 = cp[1]; q10 = cp[TT]; q11 = cp[TT + 1];
    }
    if (live) {
      float U0, U1;
      if (I == 0) { U0 = BIGC; U1 = BIGC; }
      else { U0 = bot[(s - 1) & 1][I - 1][0]; U1 = bot[(s - 1) & 1][I - 1][1]; }
      float c00 = dpcell(d00, D0, U0, L0);
      float c01 = dpcell(d01, U0, U1, c00);
      float c10 = dpcell(d10, L0, c00, L1);
      float c11 = dpcell(d11, c00, c01, c10);
      if (!row1ok)          { c10 = BIGC; c11 = BIGC; }
      if (2 * J + 1 >= lb)  { c01 = BIGC; c11 = BIGC; }
      if (I == Itar && J == Jtar) {
        float u = ((la - 1) & 1) ? (((lb - 1) & 1) ? c11 : c10)
                                 : (((lb - 1) & 1) ? c01 : c00);
        sdt[blk] = u * USCALE;   // back to R-units
      }
      bot[s & 1][I][0] = c10;
      bot[s & 1][I][1] = c11;
      L0 = c01; L1 = c11; D0 = U1;
    }
    if (pf) { d00 = q00; d01 = q01; d10 = q10; d11 = q11; }
    __syncthreads();
  }
}

// ---------------------------------------------------------------------------
// Kernel 3: 44x44 Gram over K = 32768 (rows w*16+s, s<11)
// grid (11,11); block 256; each block owns a 4x4 tile, deterministic reduction
// ---------------------------------------------------------------------------
__global__ __launch_bounds__(256) void gram_kernel(const float* __restrict__ data,
                                                   float* __restrict__ gram) {
  int bx = blockIdx.x, by = blockIdx.y;
  int t = threadIdx.x;
  const float* Ar[4]; const float* Br[4];
  for (int a = 0; a < 4; ++a) {
    int gx = bx * 4 + a;
    Ar[a] = data + (size_t)((gx / 11) * STP + gx % 11) * (TT * DD);
    int gy = by * 4 + a;
    Br[a] = data + (size_t)((gy / 11) * STP + gy % 11) * (TT * DD);
  }
  float acc[4][4];
  for (int a = 0; a < 4; ++a) for (int b = 0; b < 4; ++b) acc[a][b] = 0.f;
  for (int k = t * 4; k < TT * DD; k += 1024) {
    float4 av[4], bv[4];
    for (int a = 0; a < 4; ++a) av[a] = *(const float4*)(Ar[a] + k);
    for (int b = 0; b < 4; ++b) bv[b] = *(const float4*)(Br[b] + k);
    for (int a = 0; a < 4; ++a)
      for (int b = 0; b < 4; ++b)
        acc[a][b] += av[a].x * bv[b].x + av[a].y * bv[b].y +
                     av[a].z * bv[b].z + av[a].w * bv[b].w;
  }
  __shared__ float red[4][16];
  int wave = t >> 6, lane = t & 63;
  for (int a = 0; a < 4; ++a)
    for (int b = 0; b < 4; ++b) {
      float v = acc[a][b];
      for (int off = 32; off > 0; off >>= 1) v += __shfl_down(v, off);
      if (lane == 0) red[wave][a * 4 + b] = v;
    }
  __syncthreads();
  if (t < 16) {
    float v = red[0][t] + red[1][t] + red[2][t] + red[3][t];
    int a = t >> 2, b = t & 3;
    gram[(size_t)(bx * 4 + a) * 44 + by * 4 + b] = v;
  }
}

// ---------------------------------------------------------------------------
// Kernel 4: final combine. block 640 = 10 waves; waves 0..8: one MMD pair each;
// wave 9: triplet losses; thread 0 writes the scalar.
// ---------------------------------------------------------------------------
__global__ __launch_bounds__(640) void final_kernel(const float* __restrict__ sdt,
                                                    const int* __restrict__ lens,
                                                    const float* __restrict__ gram,
                                                    float* __restrict__ out) {
  __shared__ float partial[16];
  int t = threadIdx.x, wave = t >> 6, lane = t & 63;
  if (wave < 9) {
    const int piA[9] = {0, 0, 0, 1, 1, 2, 2, 3, 3};
    const int pjA[9] = {1, 2, 3, 2, 3, 1, 3, 1, 2};
    int P = piA[wave], Q = pjA[wave];
    // pass 1: sum of l2 over 22x22
    float s1 = 0.f;
    for (int c = lane; c < 484; c += 64) {
      int i = c / 22, jj = c - (c / 22) * 22;
      int gi = (i < 11) ? P * 11 + i : Q * 11 + (i - 11);
      int gj = (jj < 11) ? P * 11 + jj : Q * 11 + (jj - 11);
      s1 += gram[gi * 44 + gi] + gram[gj * 44 + gj] - 2.f * gram[gi * 44 + gj];
    }
    for (int off = 32; off > 0; off >>= 1) s1 += __shfl_down(s1, off);
    s1 = __shfl(s1, 0);
    float bw = s1 / 462.0f * 0.25f;     // /(ns^2-ns) then / KMUL^(KNUM//2)=4
    float inv[5];
    float b = bw;
    for (int q = 0; q < 5; ++q) { inv[q] = -1.0f / b; b *= 2.0f; }
    // pass 2: signed multi-kernel sum
    float s2 = 0.f;
    for (int c = lane; c < 484; c += 64) {
      int i = c / 22, jj = c - (c / 22) * 22;
      int gi = (i < 11) ? P * 11 + i : Q * 11 + (i - 11);
      int gj = (jj < 11) ? P * 11 + jj : Q * 11 + (jj - 11);
      float l2 = gram[gi * 44 + gi] + gram[gj * 44 + gj] - 2.f * gram[gi * 44 + gj];
      float kk = 0.f;
      for (int q = 0; q < 5; ++q) kk += __expf(l2 * inv[q]);
      float sgn = ((i < 11) == (jj < 11)) ? 1.0f : -1.0f;
      s2 += sgn * kk;
    }
    for (int off = 32; off > 0; off >>= 1) s2 += __shfl_down(s2, off);
    if (lane == 0) partial[wave] = s2 / 121.0f;
  } else {
    float term = 0.f;
    if (wave == 9 && lane < 4) {
      int w = lane;
      float L0 = (float)lens[w * STP];
      float dist[15];
      for (int q = 0; q < 15; ++q)
        dist[q] = sdt[w * NPJ + q] / (L0 + (float)lens[w * STP + 1 + q]);
      float ca = 0.f, cb = 0.f;
      for (int a = 0; a < 6; ++a) ca += dist[a];
      ca *= (1.0f / 6.0f);
      for (int bq = 6; bq < 11; ++bq) cb += dist[bq];
      cb *= (1.0f / 5.0f);
      float lksum = 0.f; int nz = 0;
      for (int a = 0; a < 6; ++a)
        for (int bq = 6; bq < 15; ++bq) {
          float x = dist[a] + 1.0f - dist[bq];   // MARGIN = 1.0
          if (x > 0.f) { lksum += x; nz += 1; }
        }
      float intra = 0.f;
      for (int a = 0; a < 6; ++a) intra += dist[a] - ca;
      float inter = fmaxf(0.f, 1.0f - fabsf(ca - cb));  // BETA = 1.0
      term = lksum / (float)(nz + 1) + intra * 0.1f + inter * 0.1f;  // P=R=0.1
    }
    if (wave == 9) {
      term += __shfl_down(term, 1);
      term += __shfl_down(term, 2);
      if (lane == 0) partial[9] = term * 0.25f;   // mean over NW=4
    }
  }
  __syncthreads();
  if (t == 0) {
    float mx = 0.0f;                               // zero-pad in the max
    for (int p = 0; p < 9; ++p) mx = fmaxf(mx, partial[p]);
    out[0] = partial[9] + 0.01f * mx;              // ALPHA = 0.01
  }
}

// ---------------------------------------------------------------------------
extern "C" void kernel_launch(void* const* d_in, const int* in_sizes, int n_in,
                              void* d_out, int out_size, void* d_ws, size_t ws_size,
                              hipStream_t stream) {
  const float* data = (const float*)d_in[0];
  const int* lens = (const int*)d_in[1];
  float* out = (float*)d_out;

  float* sdtb  = (float*)d_ws;                      // 60 floats
  float* gramb = sdtb + 64;                         // 44*44 floats
  float* costb = (float*)((char*)d_ws + 8192);      // cost chunks

  size_t avail = (ws_size > 8192) ? (ws_size - 8192) : 0;
  int chunk = (int)(avail / ((size_t)CMAT * sizeof(float)));
  if (chunk < 1) chunk = 1;
  if (chunk > NBLK) chunk = NBLK;

  for (int base = 0; base < NBLK; base += chunk) {
    int n = NBLK - base;
    if (n > chunk) n = chunk;
    cost_kernel<<<dim3(16, 16, n), 256, 0, stream>>>(data, lens, costb, base);
    dp_kernel<<<n, 256, 0, stream>>>(costb, lens, sdtb, base);
  }
  gram_kernel<<<dim3(11, 11), 256, 0, stream>>>(data, gramb);
  final_kernel<<<1, 640, 0, stream>>>(sdtb, lens, gramb, out);
}

// Round 2
// 288.798 us; speedup vs baseline: 1.2415x; 1.2415x over previous
//
#include <hip/hip_runtime.h>
#include <hip/hip_bf16.h>

// Problem constants
#define TT   512
#define DD   64
#define NWK  4
#define STP  16
#define NPJ  15          // others per w
#define NBLK 60          // NWK * NPJ
#define CMAT (TT * TT)   // floats per cost matrix
// u-domain scale: u = R / (gamma * ln2), gamma = 5
#define CSCALE 0.2885390081777927f
#define USCALE 3.4657359027997265f   // gamma * ln2
#define BIGC   2.885390081777927e8f  // 1e9 * CSCALE

#define SA 132   // LDS stride for A (128 rows + pad, keeps b128 16B-aligned)
#define SB 68    // LDS stride for B (64 rows + pad)

// ---------------------------------------------------------------------------
// Kernel 1: cost matrices, scaled by CSCALE. 128x64 tile per block, 256 thr,
// 8x4 cells per thread, k-major LDS so inner loop is 3 ds_read_b128 / 32 FMA.
// grid (8, 4, nchunk); block 256
// ---------------------------------------------------------------------------
__global__ __launch_bounds__(256) void cost_kernel(const float* __restrict__ data,
                                                   const int* __restrict__ lens,
                                                   float* __restrict__ cost, int base) {
  int blk = base + blockIdx.z;
  int w = blk / NPJ, j = blk - w * NPJ;
  int la = lens[w * STP];
  int lb = lens[w * STP + 1 + j];
  int ti = blockIdx.y, tj = blockIdx.x;   // ti: 128-row tiles, tj: 64-col tiles
  if (ti * 128 >= la || tj * 64 >= lb) return;

  __shared__ float As[DD][SA];   // k-major: As[k][r], r in [0,128)
  __shared__ float Bs[DD][SB];   // k-major: Bs[k][c], c in [0,64)
  __shared__ float a2[128], b2[64];

  const float* Abase = data + ((size_t)(w * STP) * TT + (size_t)ti * 128) * DD;
  const float* Bbase = data + ((size_t)(w * STP + 1 + j) * TT + (size_t)tj * 64) * DD;
  int t = threadIdx.x;

  #pragma unroll
  for (int i = 0; i < 8; ++i) {          // A: 128 rows x 16 float4
    int idx = t + i * 256;
    int r = idx >> 4, k4 = (idx & 15) << 2;
    float4 v = *(const float4*)(Abase + r * DD + k4);
    As[k4][r] = v.x; As[k4 + 1][r] = v.y; As[k4 + 2][r] = v.z; As[k4 + 3][r] = v.w;
  }
  #pragma unroll
  for (int i = 0; i < 4; ++i) {          // B: 64 rows x 16 float4
    int idx = t + i * 256;
    int r = idx >> 4, k4 = (idx & 15) << 2;
    float4 v = *(const float4*)(Bbase + r * DD + k4);
    Bs[k4][r] = v.x; Bs[k4 + 1][r] = v.y; Bs[k4 + 2][r] = v.z; Bs[k4 + 3][r] = v.w;
  }
  __syncthreads();
  if (t < 128) {
    float s = 0.f;
    for (int k = 0; k < DD; ++k) { float x = As[k][t]; s += x * x; }
    a2[t] = s;
  } else if (t < 192) {
    float s = 0.f;
    for (int k = 0; k < DD; ++k) { float x = Bs[k][t - 128]; s += x * x; }
    b2[t - 128] = s;
  }
  __syncthreads();

  int r0 = (t >> 4) << 3;   // 8 consecutive rows
  int c0 = (t & 15) << 2;   // 4 consecutive cols
  float acc[8][4];
  #pragma unroll
  for (int i = 0; i < 8; ++i)
    #pragma unroll
    for (int q = 0; q < 4; ++q) acc[i][q] = 0.f;

  #pragma unroll 2
  for (int k = 0; k < DD; ++k) {
    float4 aL = *(const float4*)&As[k][r0];
    float4 aH = *(const float4*)&As[k][r0 + 4];
    float4 bb = *(const float4*)&Bs[k][c0];
    float a[8] = {aL.x, aL.y, aL.z, aL.w, aH.x, aH.y, aH.z, aH.w};
    float b[4] = {bb.x, bb.y, bb.z, bb.w};
    #pragma unroll
    for (int i = 0; i < 8; ++i)
      #pragma unroll
      for (int q = 0; q < 4; ++q)
        acc[i][q] += a[i] * b[q];
  }

  float* Cp0 = cost + (size_t)blockIdx.z * CMAT + (size_t)(ti * 128 + r0) * TT + tj * 64 + c0;
  #pragma unroll
  for (int i = 0; i < 8; ++i) {
    float ar = a2[r0 + i];
    float4 o;
    o.x = (ar + b2[c0]     - 2.f * acc[i][0]) * CSCALE;
    o.y = (ar + b2[c0 + 1] - 2.f * acc[i][1]) * CSCALE;
    o.z = (ar + b2[c0 + 2] - 2.f * acc[i][2]) * CSCALE;
    o.w = (ar + b2[c0 + 3] - 2.f * acc[i][3]) * CSCALE;
    *(float4*)(Cp0 + (size_t)i * TT) = o;
  }
}

// ---------------------------------------------------------------------------
// Soft-DTW DP cell in u-units: u = dc + min - log2(1 + 2^(min-med) + 2^(min-max))
// ---------------------------------------------------------------------------
__device__ __forceinline__ float dpcell(float dc, float a, float b, float c) {
  float mn = fminf(fminf(a, b), c);
  float mx = fmaxf(fmaxf(a, b), c);
  float md = __builtin_amdgcn_fmed3f(a, b, c);
  float e = 1.0f + __builtin_amdgcn_exp2f(mn - md) + __builtin_amdgcn_exp2f(mn - mx);
  return dc + mn - __builtin_amdgcn_logf(e);
}

// cost-tile fetch for DP thread (rows 2I,2I+1; tile col J)
__device__ __forceinline__ float4 ldq(const float* __restrict__ Crow, int J, int nJ, bool act) {
  float4 v = make_float4(0.f, 0.f, 0.f, 0.f);
  if (act && (unsigned)J < (unsigned)nJ) {
    const float* cp = Crow + 2 * J;
    v.x = cp[0]; v.y = cp[1]; v.z = cp[TT]; v.w = cp[TT + 1];
  }
  return v;
}

// ---------------------------------------------------------------------------
// Kernel 2: fused DP (blocks [0,ndp)) + gram (blocks [ndp, ndp+121)).
// DP: one block per (w,j); 2x2 tile/thread; raw lgkm-only barrier so the
// 4-deep global prefetch ring survives across steps.
// ---------------------------------------------------------------------------
__global__ __launch_bounds__(256) void dp_gram_kernel(const float* __restrict__ cost,
                                                      const int* __restrict__ lens,
                                                      const float* __restrict__ data,
                                                      float* __restrict__ sdt,
                                                      float* __restrict__ gram,
                                                      int base, int ndp) {
  __shared__ float bot[2][256][2];
  __shared__ float red[4][16];
  int bid = blockIdx.x;

  if (bid >= ndp) {
    // ---------------- gram path: 44x44 Gram over K = 32768 ----------------
    int g = bid - ndp;
    int bx = g / 11, by = g - bx * 11;
    int t = threadIdx.x;
    const float* Ar[4]; const float* Br[4];
    #pragma unroll
    for (int a = 0; a < 4; ++a) {
      int gx = bx * 4 + a;
      Ar[a] = data + (size_t)((gx / 11) * STP + gx % 11) * (TT * DD);
      int gy = by * 4 + a;
      Br[a] = data + (size_t)((gy / 11) * STP + gy % 11) * (TT * DD);
    }
    float acc[4][4];
    #pragma unroll
    for (int a = 0; a < 4; ++a)
      #pragma unroll
      for (int b = 0; b < 4; ++b) acc[a][b] = 0.f;
    for (int k = t * 4; k < TT * DD; k += 1024) {
      float4 av[4], bv[4];
      #pragma unroll
      for (int a = 0; a < 4; ++a) av[a] = *(const float4*)(Ar[a] + k);
      #pragma unroll
      for (int b = 0; b < 4; ++b) bv[b] = *(const float4*)(Br[b] + k);
      #pragma unroll
      for (int a = 0; a < 4; ++a)
        #pragma unroll
        for (int b = 0; b < 4; ++b)
          acc[a][b] += av[a].x * bv[b].x + av[a].y * bv[b].y +
                       av[a].z * bv[b].z + av[a].w * bv[b].w;
    }
    int wave = t >> 6, lane = t & 63;
    #pragma unroll
    for (int a = 0; a < 4; ++a)
      #pragma unroll
      for (int b = 0; b < 4; ++b) {
        float v = acc[a][b];
        for (int off = 32; off > 0; off >>= 1) v += __shfl_down(v, off);
        if (lane == 0) red[wave][a * 4 + b] = v;
      }
    __syncthreads();
    if (t < 16) {
      float v = red[0][t] + red[1][t] + red[2][t] + red[3][t];
      int a = t >> 2, b = t & 3;
      gram[(size_t)(bx * 4 + a) * 44 + by * 4 + b] = v;
    }
    return;
  }

  // -------------------------- DP path --------------------------
  int blk = base + bid;
  int w = blk / NPJ, j = blk - w * NPJ;
  int la = lens[w * STP];
  int lb = lens[w * STP + 1 + j];
  const float* C = cost + (size_t)bid * CMAT;
  int nI = (la + 1) >> 1, nJ = (lb + 1) >> 1;
  int I = threadIdx.x;
  int steps = nI + nJ - 1;
  int steps4 = (steps + 3) & ~3;

  bool act = (I < nI);
  bool row1ok = (2 * I + 1) < la;
  int Itar = (la - 1) >> 1, Jtar = (lb - 1) >> 1;

  float L0 = BIGC, L1 = BIGC, D0 = (I == 0) ? 0.0f : BIGC;
  float res = 0.f;
  const float* Crow = C + (size_t)(2 * I) * TT;

  // 4-deep prefetch ring: q_u holds the cost tile for step s with s%4==u
  float4 q0 = ldq(Crow, 0 - I, nJ, act);
  float4 q1 = ldq(Crow, 1 - I, nJ, act);
  float4 q2 = ldq(Crow, 2 - I, nJ, act);
  float4 q3 = ldq(Crow, 3 - I, nJ, act);

  auto body = [&](int s, float4& q) {
    int J = s - I;
    bool live = act && ((unsigned)J < (unsigned)nJ);
    float d00 = q.x, d01 = q.y, d10 = q.z, d11 = q.w;
    q = ldq(Crow, s + 4 - I, nJ, act);   // refill for step s+4 (stays in flight)
    if (live) {
      float U0 = BIGC, U1 = BIGC;
      if (I > 0) { U0 = bot[(s - 1) & 1][I - 1][0]; U1 = bot[(s - 1) & 1][I - 1][1]; }
      float c00 = dpcell(d00, D0, U0, L0);
      float c01 = dpcell(d01, U0, U1, c00);
      float c10 = dpcell(d10, L0, c00, L1);
      float c11 = dpcell(d11, c00, c01, c10);
      if (!row1ok)        { c10 = BIGC; c11 = BIGC; }
      if (2 * J + 1 >= lb){ c01 = BIGC; c11 = BIGC; }
      if ((I == Itar) & (J == Jtar)) {
        res = ((la - 1) & 1) ? (((lb - 1) & 1) ? c11 : c10)
                             : (((lb - 1) & 1) ? c01 : c00);
      }
      bot[s & 1][I][0] = c10;
      bot[s & 1][I][1] = c11;
      L0 = c01; L1 = c11; D0 = U1;
    }
    // lgkm-only barrier: do NOT drain vmcnt (keeps prefetch ring in flight)
    asm volatile("s_waitcnt lgkmcnt(0)\n\ts_barrier" ::: "memory");
  };

  for (int s0 = 0; s0 < steps4; s0 += 4) {
    body(s0, q0); body(s0 + 1, q1); body(s0 + 2, q2); body(s0 + 3, q3);
  }
  if (act && I == Itar) sdt[blk] = res * USCALE;
}

// ---------------------------------------------------------------------------
// Kernel 4: final combine. block 640 = 10 waves; waves 0..8: one MMD pair each;
// wave 9: triplet losses; thread 0 writes the scalar.
// ---------------------------------------------------------------------------
__global__ __launch_bounds__(640) void final_kernel(const float* __restrict__ sdt,
                                                    const int* __restrict__ lens,
                                                    const float* __restrict__ gram,
                                                    float* __restrict__ out) {
  __shared__ float partial[16];
  int t = threadIdx.x, wave = t >> 6, lane = t & 63;
  if (wave < 9) {
    const int piA[9] = {0, 0, 0, 1, 1, 2, 2, 3, 3};
    const int pjA[9] = {1, 2, 3, 2, 3, 1, 3, 1, 2};
    int P = piA[wave], Q = pjA[wave];
    float s1 = 0.f;
    for (int c = lane; c < 484; c += 64) {
      int i = c / 22, jj = c - (c / 22) * 22;
      int gi = (i < 11) ? P * 11 + i : Q * 11 + (i - 11);
      int gj = (jj < 11) ? P * 11 + jj : Q * 11 + (jj - 11);
      s1 += gram[gi * 44 + gi] + gram[gj * 44 + gj] - 2.f * gram[gi * 44 + gj];
    }
    for (int off = 32; off > 0; off >>= 1) s1 += __shfl_down(s1, off);
    s1 = __shfl(s1, 0);
    float bw = s1 / 462.0f * 0.25f;     // /(ns^2-ns) then / KMUL^(KNUM//2)=4
    float inv[5];
    float b = bw;
    #pragma unroll
    for (int q = 0; q < 5; ++q) { inv[q] = -1.0f / b; b *= 2.0f; }
    float s2 = 0.f;
    for (int c = lane; c < 484; c += 64) {
      int i = c / 22, jj = c - (c / 22) * 22;
      int gi = (i < 11) ? P * 11 + i : Q * 11 + (i - 11);
      int gj = (jj < 11) ? P * 11 + jj : Q * 11 + (jj - 11);
      float l2 = gram[gi * 44 + gi] + gram[gj * 44 + gj] - 2.f * gram[gi * 44 + gj];
      float kk = 0.f;
      #pragma unroll
      for (int q = 0; q < 5; ++q) kk += __expf(l2 * inv[q]);
      float sgn = ((i < 11) == (jj < 11)) ? 1.0f : -1.0f;
      s2 += sgn * kk;
    }
    for (int off = 32; off > 0; off >>= 1) s2 += __shfl_down(s2, off);
    if (lane == 0) partial[wave] = s2 / 121.0f;
  } else {
    float term = 0.f;
    if (wave == 9 && lane < 4) {
      int w = lane;
      float L0 = (float)lens[w * STP];
      float dist[15];
      for (int q = 0; q < 15; ++q)
        dist[q] = sdt[w * NPJ + q] / (L0 + (float)lens[w * STP + 1 + q]);
      float ca = 0.f, cb = 0.f;
      for (int a = 0; a < 6; ++a) ca += dist[a];
      ca *= (1.0f / 6.0f);
      for (int bq = 6; bq < 11; ++bq) cb += dist[bq];
      cb *= (1.0f / 5.0f);
      float lksum = 0.f; int nz = 0;
      for (int a = 0; a < 6; ++a)
        for (int bq = 6; bq < 15; ++bq) {
          float x = dist[a] + 1.0f - dist[bq];   // MARGIN = 1.0
          if (x > 0.f) { lksum += x; nz += 1; }
        }
      float intra = 0.f;
      for (int a = 0; a < 6; ++a) intra += dist[a] - ca;
      float inter = fmaxf(0.f, 1.0f - fabsf(ca - cb));  // BETA = 1.0
      term = lksum / (float)(nz + 1) + intra * 0.1f + inter * 0.1f;  // P=R=0.1
    }
    if (wave == 9) {
      term += __shfl_down(term, 1);
      term += __shfl_down(term, 2);
      if (lane == 0) partial[9] = term * 0.25f;   // mean over NW=4
    }
  }
  __syncthreads();
  if (t == 0) {
    float mx = 0.0f;                               // zero-pad in the max
    for (int p = 0; p < 9; ++p) mx = fmaxf(mx, partial[p]);
    out[0] = partial[9] + 0.01f * mx;              // ALPHA = 0.01
  }
}

// ---------------------------------------------------------------------------
extern "C" void kernel_launch(void* const* d_in, const int* in_sizes, int n_in,
                              void* d_out, int out_size, void* d_ws, size_t ws_size,
                              hipStream_t stream) {
  const float* data = (const float*)d_in[0];
  const int* lens = (const int*)d_in[1];
  float* out = (float*)d_out;

  float* sdtb  = (float*)d_ws;                      // 60 floats
  float* gramb = sdtb + 64;                         // 44*44 floats
  float* costb = (float*)((char*)d_ws + 8192);      // cost chunks

  size_t avail = (ws_size > 8192) ? (ws_size - 8192) : 0;
  int chunk = (int)(avail / ((size_t)CMAT * sizeof(float)));
  if (chunk < 1) chunk = 1;
  if (chunk > NBLK) chunk = NBLK;

  bool first = true;
  for (int base = 0; base < NBLK; base += chunk) {
    int n = NBLK - base;
    if (n > chunk) n = chunk;
    cost_kernel<<<dim3(8, 4, n), 256, 0, stream>>>(data, lens, costb, base);
    int extra = first ? 121 : 0;   // fuse gram onto otherwise-idle CUs
    dp_gram_kernel<<<n + extra, 256, 0, stream>>>(costb, lens, data, sdtb, gramb, base, n);
    first = false;
  }
  final_kernel<<<1, 640, 0, stream>>>(sdtb, lens, gramb, out);
}

// Round 3
// 218.066 us; speedup vs baseline: 1.6442x; 1.3244x over previous
//
#include <hip/hip_runtime.h>
#include <hip/hip_bf16.h>

// Problem constants
#define TT   512
#define DD   64
#define NWK  4
#define STP  16
#define NPJ  15          // others per w
#define NBLK 60          // NWK * NPJ
#define CMAT (TT * TT)   // floats per cost matrix
// u-domain scale: u = R / (gamma * ln2), gamma = 5
#define CSCALE 0.2885390081777927f
#define USCALE 3.4657359027997265f   // gamma * ln2
#define BIGC   2.885390081777927e8f  // 1e9 * CSCALE

#define SA 132   // LDS leading stride (128 + 4 pad)

// ---------------------------------------------------------------------------
// Kernel 1: cost matrices, scaled by CSCALE. 128x128 tile per block, 256 thr,
// split 4+4 register tile per thread (rows {r0..r0+3, r0+64..67} x cols same)
// so every ds_read_b128 is <=2-way bank-aliased (free). grid (4,4,n).
// ---------------------------------------------------------------------------
__global__ __launch_bounds__(256) void cost_kernel(const float* __restrict__ data,
                                                   const int* __restrict__ lens,
                                                   float* __restrict__ cost, int base) {
  int blk = base + blockIdx.z;
  int w = blk / NPJ, j = blk - w * NPJ;
  int la = lens[w * STP];
  int lb = lens[w * STP + 1 + j];
  int ti = blockIdx.y, tj = blockIdx.x;
  if (ti * 128 >= la || tj * 128 >= lb) return;

  __shared__ float As[DD][SA];   // k-major: As[k][r], r in [0,128)
  __shared__ float Bs[DD][SA];
  __shared__ float a2[128], b2[128];

  const float* A = data + ((size_t)(w * STP) * TT + (size_t)ti * 128) * DD;
  const float* B = data + ((size_t)(w * STP + 1 + j) * TT + (size_t)tj * 128) * DD;
  int t = threadIdx.x;

  #pragma unroll
  for (int i = 0; i < 8; ++i) {
    int idx = t + i * 256;        // [0, 2048)
    int r = idx & 127;            // row within tile
    int kq = idx >> 7;            // float4 index along k, [0,16)
    float4 va = *(const float4*)(A + r * DD + kq * 4);
    As[kq * 4 + 0][r] = va.x; As[kq * 4 + 1][r] = va.y;
    As[kq * 4 + 2][r] = va.z; As[kq * 4 + 3][r] = va.w;
    float4 vb = *(const float4*)(B + r * DD + kq * 4);
    Bs[kq * 4 + 0][r] = vb.x; Bs[kq * 4 + 1][r] = vb.y;
    Bs[kq * 4 + 2][r] = vb.z; Bs[kq * 4 + 3][r] = vb.w;
  }
  __syncthreads();
  if (t < 128) {
    float s = 0.f;
    for (int k = 0; k < DD; ++k) { float x = As[k][t]; s += x * x; }
    a2[t] = s;
  } else {
    float s = 0.f;
    for (int k = 0; k < DD; ++k) { float x = Bs[k][t - 128]; s += x * x; }
    b2[t - 128] = s;
  }
  __syncthreads();

  int r0 = (t >> 4) << 2;   // {0,4,...,60}
  int c0 = (t & 15) << 2;   // {0,4,...,60}
  float acc[8][8];
  #pragma unroll
  for (int i = 0; i < 8; ++i)
    #pragma unroll
    for (int q = 0; q < 8; ++q) acc[i][q] = 0.f;

  #pragma unroll 2
  for (int k = 0; k < DD; ++k) {
    float4 aL = *(const float4*)&As[k][r0];
    float4 aH = *(const float4*)&As[k][r0 + 64];
    float4 bL = *(const float4*)&Bs[k][c0];
    float4 bH = *(const float4*)&Bs[k][c0 + 64];
    float a[8] = {aL.x, aL.y, aL.z, aL.w, aH.x, aH.y, aH.z, aH.w};
    float b[8] = {bL.x, bL.y, bL.z, bL.w, bH.x, bH.y, bH.z, bH.w};
    #pragma unroll
    for (int i = 0; i < 8; ++i)
      #pragma unroll
      for (int q = 0; q < 8; ++q)
        acc[i][q] += a[i] * b[q];
  }

  float* Cbase = cost + (size_t)blockIdx.z * CMAT;
  #pragma unroll
  for (int i = 0; i < 8; ++i) {
    int rr = (i < 4) ? (r0 + i) : (r0 + 60 + i);   // r0+64+(i-4)
    float ar = a2[rr];
    float* Crow = Cbase + (size_t)(ti * 128 + rr) * TT + tj * 128;
    float4 o;
    o.x = (ar + b2[c0 + 0] - 2.f * acc[i][0]) * CSCALE;
    o.y = (ar + b2[c0 + 1] - 2.f * acc[i][1]) * CSCALE;
    o.z = (ar + b2[c0 + 2] - 2.f * acc[i][2]) * CSCALE;
    o.w = (ar + b2[c0 + 3] - 2.f * acc[i][3]) * CSCALE;
    *(float4*)(Crow + c0) = o;
    float4 o2;
    o2.x = (ar + b2[c0 + 64] - 2.f * acc[i][4]) * CSCALE;
    o2.y = (ar + b2[c0 + 65] - 2.f * acc[i][5]) * CSCALE;
    o2.z = (ar + b2[c0 + 66] - 2.f * acc[i][6]) * CSCALE;
    o2.w = (ar + b2[c0 + 67] - 2.f * acc[i][7]) * CSCALE;
    *(float4*)(Crow + c0 + 64) = o2;
  }
}

// ---------------------------------------------------------------------------
// Soft-DTW DP cell in u-units: u = dc + min - log2(1 + 2^(min-med) + 2^(min-max))
// ---------------------------------------------------------------------------
__device__ __forceinline__ float dpcell(float dc, float a, float b, float c) {
  float mn = fminf(fminf(a, b), c);
  float mx = fmaxf(fmaxf(a, b), c);
  float md = __builtin_amdgcn_fmed3f(a, b, c);
  float e = 1.0f + __builtin_amdgcn_exp2f(mn - md) + __builtin_amdgcn_exp2f(mn - mx);
  return dc + mn - __builtin_amdgcn_logf(e);
}

// ---------------------------------------------------------------------------
// Kernel 2: fused DP (blocks [0,ndp)) + gram (blocks [ndp, ndp+121)).
// DP: barrier-free systolic pipeline. 4 waves; wave q owns cols [128q,128q+128);
// lane owns 2 cols, lane-skew 1 row/lane (intra-wave boundary via shfl_up);
// wave->wave boundary via write-once LDS column + spin flags (8-row groups).
// ---------------------------------------------------------------------------
__global__ __launch_bounds__(256) void dp_gram_kernel(const float* __restrict__ cost,
                                                      const int* __restrict__ lens,
                                                      const float* __restrict__ data,
                                                      float* __restrict__ sdt,
                                                      float* __restrict__ gram,
                                                      int base, int ndp) {
  int bid = blockIdx.x;

  if (bid >= ndp) {
    // ---------------- gram path: 44x44 Gram over K = 32768 ----------------
    __shared__ float red[4][16];
    int g = bid - ndp;
    int bx = g / 11, by = g - bx * 11;
    int t = threadIdx.x;
    const float* Ar[4]; const float* Br[4];
    #pragma unroll
    for (int a = 0; a < 4; ++a) {
      int gx = bx * 4 + a;
      Ar[a] = data + (size_t)((gx / 11) * STP + gx % 11) * (TT * DD);
      int gy = by * 4 + a;
      Br[a] = data + (size_t)((gy / 11) * STP + gy % 11) * (TT * DD);
    }
    float acc[4][4];
    #pragma unroll
    for (int a = 0; a < 4; ++a)
      #pragma unroll
      for (int b = 0; b < 4; ++b) acc[a][b] = 0.f;
    for (int k = t * 4; k < TT * DD; k += 1024) {
      float4 av[4], bv[4];
      #pragma unroll
      for (int a = 0; a < 4; ++a) av[a] = *(const float4*)(Ar[a] + k);
      #pragma unroll
      for (int b = 0; b < 4; ++b) bv[b] = *(const float4*)(Br[b] + k);
      #pragma unroll
      for (int a = 0; a < 4; ++a)
        #pragma unroll
        for (int b = 0; b < 4; ++b)
          acc[a][b] += av[a].x * bv[b].x + av[a].y * bv[b].y +
                       av[a].z * bv[b].z + av[a].w * bv[b].w;
    }
    int wave = t >> 6, lane = t & 63;
    #pragma unroll
    for (int a = 0; a < 4; ++a)
      #pragma unroll
      for (int b = 0; b < 4; ++b) {
        float v = acc[a][b];
        for (int off = 32; off > 0; off >>= 1) v += __shfl_down(v, off);
        if (lane == 0) red[wave][a * 4 + b] = v;
      }
    __syncthreads();
    if (t < 16) {
      float v = red[0][t] + red[1][t] + red[2][t] + red[3][t];
      int a = t >> 2, b = t & 3;
      gram[(size_t)(bx * 4 + a) * 44 + by * 4 + b] = v;
    }
    return;
  }

  // -------------------------- DP path --------------------------
  __shared__ float bufB[3][600];   // boundary column per wave (write-once)
  __shared__ int flags[4];

  if (threadIdx.x < 4) flags[threadIdx.x] = 0;
  __syncthreads();

  int blk = base + bid;
  int w = blk / NPJ, j = blk - w * NPJ;
  int la = lens[w * STP];
  int lb = lens[w * STP + 1 + j];
  const float* C = cost + (size_t)bid * CMAT;

  int q = threadIdx.x >> 6, ln = threadIdx.x & 63;
  int c0 = q * 128 + ln * 2;
  const float* Cp = C + c0;

  // target cell (la-1, lb-1)
  int qt = (lb - 1) >> 7;
  int lt = ((lb - 1) >> 1) & 63;
  int par = (lb - 1) & 1;
  int rt = la - 1;
  bool isT = (q == qt) && (ln == lt);

  float U0 = BIGC, U1 = BIGC;          // own cols, previous row
  float NL = BIGC;                     // left neighbor value, current row
  float NLd = (q == 0 && ln == 0) ? 0.0f : BIGC;  // left-diag (prev row)
  float v1s = BIGC;                    // last computed right-col value
  float res = 0.0f;

  int ngrp = (la + 70) >> 3;

  // cost regs: cc = current group (rows 8g+k-ln), cn = next group prefetch
  float2 cc[8], cn[8];
  #pragma unroll
  for (int k = 0; k < 8; ++k) {
    int rr = k - ln; rr = rr < 0 ? 0 : (rr > 511 ? 511 : rr);
    cc[k] = *(const float2*)(Cp + (size_t)rr * TT);
  }
  float bb[8];

  for (int g = 0; g < ngrp; ++g) {
    if (q > 0) {
      int need = 8 * g + 9; if (need > la) need = la;
      while (*(volatile int*)&flags[q - 1] < need) __builtin_amdgcn_s_sleep(2);
      __threadfence_block();
      #pragma unroll
      for (int k = 0; k < 8; ++k) bb[k] = bufB[q - 1][8 * g + 1 + k];
      if (g == 0) {
        float nl0 = bufB[q - 1][0];
        if (ln == 0) NL = nl0;
      }
    }
    // prefetch cost for next group (clamped rows; stays in flight this group)
    #pragma unroll
    for (int k = 0; k < 8; ++k) {
      int rr = 8 * (g + 1) + k - ln; rr = rr < 0 ? 0 : (rr > 511 ? 511 : rr);
      cn[k] = *(const float2*)(Cp + (size_t)rr * TT);
    }
    #pragma unroll
    for (int k = 0; k < 8; ++k) {
      int r = 8 * g + k - ln;
      bool act = ((unsigned)r < 512u);
      if (act) {
        float v0 = dpcell(cc[k].x, NLd, U0, NL);
        float v1 = dpcell(cc[k].y, U0, U1, v0);
        if (isT & (r == rt)) res = par ? v1 : v0;
        NLd = NL; U0 = v0; U1 = v1; v1s = v1;
        if (q < 3 && ln == 63) {
          bufB[q][r] = v1;
          if ((r & 7) == 7) {
            __threadfence_block();
            *(volatile int*)&flags[q] = r + 1;
          }
        }
      }
      float nb = __shfl_up(v1s, 1);
      if (ln == 0) nb = (q == 0) ? BIGC : bb[k];
      NL = nb;
    }
    #pragma unroll
    for (int k = 0; k < 8; ++k) cc[k] = cn[k];
  }
  if (q < 3 && ln == 63) {
    __threadfence_block();
    *(volatile int*)&flags[q] = 512;   // release any remaining pollers
  }
  if (isT) sdt[blk] = res * USCALE;
}

// ---------------------------------------------------------------------------
// Kernel 4: final combine. block 640 = 10 waves; waves 0..8: one MMD pair each;
// wave 9: triplet losses; thread 0 writes the scalar.
// ---------------------------------------------------------------------------
__global__ __launch_bounds__(640) void final_kernel(const float* __restrict__ sdt,
                                                    const int* __restrict__ lens,
                                                    const float* __restrict__ gram,
                                                    float* __restrict__ out) {
  __shared__ float partial[16];
  int t = threadIdx.x, wave = t >> 6, lane = t & 63;
  if (wave < 9) {
    const int piA[9] = {0, 0, 0, 1, 1, 2, 2, 3, 3};
    const int pjA[9] = {1, 2, 3, 2, 3, 1, 3, 1, 2};
    int P = piA[wave], Q = pjA[wave];
    float s1 = 0.f;
    for (int c = lane; c < 484; c += 64) {
      int i = c / 22, jj = c - (c / 22) * 22;
      int gi = (i < 11) ? P * 11 + i : Q * 11 + (i - 11);
      int gj = (jj < 11) ? P * 11 + jj : Q * 11 + (jj - 11);
      s1 += gram[gi * 44 + gi] + gram[gj * 44 + gj] - 2.f * gram[gi * 44 + gj];
    }
    for (int off = 32; off > 0; off >>= 1) s1 += __shfl_down(s1, off);
    s1 = __shfl(s1, 0);
    float bw = s1 / 462.0f * 0.25f;     // /(ns^2-ns) then / KMUL^(KNUM//2)=4
    float inv[5];
    float b = bw;
    #pragma unroll
    for (int qq = 0; qq < 5; ++qq) { inv[qq] = -1.0f / b; b *= 2.0f; }
    float s2 = 0.f;
    for (int c = lane; c < 484; c += 64) {
      int i = c / 22, jj = c - (c / 22) * 22;
      int gi = (i < 11) ? P * 11 + i : Q * 11 + (i - 11);
      int gj = (jj < 11) ? P * 11 + jj : Q * 11 + (jj - 11);
      float l2 = gram[gi * 44 + gi] + gram[gj * 44 + gj] - 2.f * gram[gi * 44 + gj];
      float kk = 0.f;
      #pragma unroll
      for (int qq = 0; qq < 5; ++qq) kk += __expf(l2 * inv[qq]);
      float sgn = ((i < 11) == (jj < 11)) ? 1.0f : -1.0f;
      s2 += sgn * kk;
    }
    for (int off = 32; off > 0; off >>= 1) s2 += __shfl_down(s2, off);
    if (lane == 0) partial[wave] = s2 / 121.0f;
  } else {
    float term = 0.f;
    if (wave == 9 && lane < 4) {
      int w = lane;
      float L0 = (float)lens[w * STP];
      float dist[15];
      for (int qq = 0; qq < 15; ++qq)
        dist[qq] = sdt[w * NPJ + qq] / (L0 + (float)lens[w * STP + 1 + qq]);
      float ca = 0.f, cb = 0.f;
      for (int a = 0; a < 6; ++a) ca += dist[a];
      ca *= (1.0f / 6.0f);
      for (int bq = 6; bq < 11; ++bq) cb += dist[bq];
      cb *= (1.0f / 5.0f);
      float lksum = 0.f; int nz = 0;
      for (int a = 0; a < 6; ++a)
        for (int bq = 6; bq < 15; ++bq) {
          float x = dist[a] + 1.0f - dist[bq];   // MARGIN = 1.0
          if (x > 0.f) { lksum += x; nz += 1; }
        }
      float intra = 0.f;
      for (int a = 0; a < 6; ++a) intra += dist[a] - ca;
      float inter = fmaxf(0.f, 1.0f - fabsf(ca - cb));  // BETA = 1.0
      term = lksum / (float)(nz + 1) + intra * 0.1f + inter * 0.1f;  // P=R=0.1
    }
    if (wave == 9) {
      term += __shfl_down(term, 1);
      term += __shfl_down(term, 2);
      if (lane == 0) partial[9] = term * 0.25f;   // mean over NW=4
    }
  }
  __syncthreads();
  if (t == 0) {
    float mx = 0.0f;                               // zero-pad in the max
    for (int p = 0; p < 9; ++p) mx = fmaxf(mx, partial[p]);
    out[0] = partial[9] + 0.01f * mx;              // ALPHA = 0.01
  }
}

// ---------------------------------------------------------------------------
extern "C" void kernel_launch(void* const* d_in, const int* in_sizes, int n_in,
                              void* d_out, int out_size, void* d_ws, size_t ws_size,
                              hipStream_t stream) {
  const float* data = (const float*)d_in[0];
  const int* lens = (const int*)d_in[1];
  float* out = (float*)d_out;

  float* sdtb  = (float*)d_ws;                      // 60 floats
  float* gramb = sdtb + 64;                         // 44*44 floats
  float* costb = (float*)((char*)d_ws + 8192);      // cost chunks

  size_t avail = (ws_size > 8192) ? (ws_size - 8192) : 0;
  int chunk = (int)(avail / ((size_t)CMAT * sizeof(float)));
  if (chunk < 1) chunk = 1;
  if (chunk > NBLK) chunk = NBLK;

  bool first = true;
  for (int base = 0; base < NBLK; base += chunk) {
    int n = NBLK - base;
    if (n > chunk) n = chunk;
    cost_kernel<<<dim3(4, 4, n), 256, 0, stream>>>(data, lens, costb, base);
    int extra = first ? 121 : 0;   // fuse gram onto otherwise-idle CUs
    dp_gram_kernel<<<n + extra, 256, 0, stream>>>(costb, lens, data, sdtb, gramb, base, n);
    first = false;
  }
  final_kernel<<<1, 640, 0, stream>>>(sdtb, lens, gramb, out);
}